// Round 2
// baseline (455.540 us; speedup 1.0000x reference)
//
#include <hip/hip_runtime.h>
#include <math.h>

// Caps1D dynamic routing.
// u: [B=1024, R=2336, M=4] fp32 ; W: [K=2, R=2336, M=4, P=16] fp32
// out: classes [B, K] fp32 = norm/(1+norm) of final squash input.
//
// One block per (b,k). u_ji[r,0..15] register-resident, distributed over
// 1024 threads x 3 rows (r = tid + j*1024). ROWS=3 keeps uji at 48 VGPRs so
// the 128-VGPR cap from __launch_bounds__(1024,4) is met WITHOUT spilling
// (round-1's 512thr/ROWS=5 variant spilled 16 floats/thread -> 64 MB of
// scratch write traffic and 267us). 16 waves/CU.

#define THREADS 1024
#define ROWS 3            // ceil(2336 / 1024)
#define NWAVE (THREADS / 64)

__global__ __launch_bounds__(THREADS, 4)
void caps_routing_kernel(const float* __restrict__ u,
                         const float* __restrict__ W,
                         float* __restrict__ out)
{
    constexpr int K = 2, R = 2336, P = 16;

    const int bi   = blockIdx.x;
    const int b    = bi >> 1;
    const int k    = bi & 1;
    const int tid  = threadIdx.x;
    const int lane = tid & 63;
    const int wave = tid >> 6;

    __shared__ float redmax[NWAVE];
    __shared__ float red[NWAVE][17];   // 16 s-partials + sumexp per wave
    __shared__ float vbuf[P];

    const float4* __restrict__ u4 = (const float4*)u;
    const float4* __restrict__ w4 = (const float4*)W;

    float uji[ROWS][P];
    float brow[ROWS];

    // rows 0,1 always valid (tid+1024 < 2336); row 2 valid iff tid < 288
    const bool v2 = (tid + 2 * THREADS) < R;

    // ---- build u_ji = u[b,r,:] @ W[k,r,:,:]  (M=4 contraction) ----
    #pragma unroll
    for (int j = 0; j < ROWS; ++j) {
        const int r = tid + j * THREADS;
        const bool valid = (j < 2) | v2;
        brow[j] = valid ? 0.0f : -INFINITY;
        #pragma unroll
        for (int p = 0; p < P; ++p) uji[j][p] = 0.0f;
        if (valid) {
            float4 uu = u4[b * R + r];                 // u[b,r,0..3]
            float um[4] = {uu.x, uu.y, uu.z, uu.w};
            const int wbase = (k * R + r) * 16;        // float4 index into W row
            #pragma unroll
            for (int m = 0; m < 4; ++m) {
                #pragma unroll
                for (int q = 0; q < 4; ++q) {
                    float4 w = w4[wbase + m * 4 + q];
                    uji[j][q * 4 + 0] += um[m] * w.x;
                    uji[j][q * 4 + 1] += um[m] * w.y;
                    uji[j][q * 4 + 2] += um[m] * w.z;
                    uji[j][q * 4 + 3] += um[m] * w.w;
                }
            }
        }
    }

    // ---- 3 routing iterations ----
    for (int it = 0; it < 3; ++it) {
        float e[ROWS];
        if (it == 0) {
            // b == 0: softmax is uniform; e_r = 1 for valid rows (se = R)
            e[0] = 1.0f; e[1] = 1.0f; e[2] = v2 ? 1.0f : 0.0f;
        } else {
            // block max of logits (softmax stability)
            float mloc = fmaxf(fmaxf(brow[0], brow[1]), brow[2]);
            #pragma unroll
            for (int o = 32; o > 0; o >>= 1) mloc = fmaxf(mloc, __shfl_down(mloc, o));
            if (lane == 0) redmax[wave] = mloc;
            __syncthreads();
            float bmax = redmax[0];
            #pragma unroll
            for (int w = 1; w < NWAVE; ++w) bmax = fmaxf(bmax, redmax[w]);
            #pragma unroll
            for (int j = 0; j < ROWS; ++j) e[j] = __expf(brow[j] - bmax); // -inf -> 0
        }

        // fused weighted sums: s_p = sum_r e_r * uji[r,p], se = sum_r e_r
        float sloc[P];
        #pragma unroll
        for (int p = 0; p < P; ++p)
            sloc[p] = e[0] * uji[0][p] + e[1] * uji[1][p] + e[2] * uji[2][p];
        float seloc = e[0] + e[1] + e[2];
        #pragma unroll
        for (int o = 32; o > 0; o >>= 1) {
            seloc += __shfl_down(seloc, o);
            #pragma unroll
            for (int p = 0; p < P; ++p) sloc[p] += __shfl_down(sloc[p], o);
        }
        if (lane == 0) {
            #pragma unroll
            for (int p = 0; p < P; ++p) red[wave][p] = sloc[p];
            red[wave][16] = seloc;
        }
        __syncthreads();

        // wave 0, lanes 0..16: column sums; lanes 0..15 finish squash in parallel
        if (wave == 0 && lane < 17) {
            float col = red[0][lane];
            #pragma unroll
            for (int w = 1; w < NWAVE; ++w) col += red[w][lane];
            // norm_raw = sum_p col_p^2 over lanes 0..15 (xor net stays in [0,16))
            float nr = col * col;
            nr += __shfl_xor(nr, 1);
            nr += __shfl_xor(nr, 2);
            nr += __shfl_xor(nr, 4);
            nr += __shfl_xor(nr, 8);
            float se = __shfl(col, 16);          // lane 16 holds sum of e
            float inv_se = 1.0f / se;
            float norm = nr * inv_se * inv_se;   // |s|^2 of mean-weighted sum
            if (lane < 16) {
                // v = s * sqrt(norm)/(1+norm), with s = col/se
                float f = sqrtf(norm) / (1.0f + norm);
                vbuf[lane] = col * inv_se * f;
                if (it == 2 && lane == 0) out[b * K + k] = norm / (1.0f + norm);
            }
        }
        __syncthreads();

        // logit update: b_r += dot(u_ji[r,:], v)   (skipped on last iter)
        if (it < 2) {
            float v[P];
            #pragma unroll
            for (int p = 0; p < P; ++p) v[p] = vbuf[p];
            #pragma unroll
            for (int j = 0; j < ROWS; ++j) {
                float d = 0.0f;
                #pragma unroll
                for (int p = 0; p < P; ++p) d += uji[j][p] * v[p];
                brow[j] += d;
            }
        }
    }
}

extern "C" void kernel_launch(void* const* d_in, const int* in_sizes, int n_in,
                              void* d_out, int out_size, void* d_ws, size_t ws_size,
                              hipStream_t stream) {
    const float* u = (const float*)d_in[0];   // [1024, 2336, 4]
    const float* W = (const float*)d_in[1];   // [2, 2336, 4, 16]
    float* out = (float*)d_out;               // [1024, 2]
    caps_routing_kernel<<<dim3(2048), dim3(THREADS), 0, stream>>>(u, W, out);
}